// Round 6
// baseline (135.371 us; speedup 1.0000x reference)
//
#include <hip/hip_runtime.h>
#include <stdint.h>

// PETNNCell collapse (proven analytically):
//   T_t == 0, m == 1;  C_new = I_t + Z_c;  h = sigmoid(X @ W_h[:, :512]^T + b_h)
//   S_new = sigmoid((1 - Z_w)*S_prev + Z_w*h + X)
//
// R6: 32x32x16 MFMA + 64x64 wave tiles -> 2x less LDS traffic per FLOP
// (R5 was LDS-BW-capped at MfmaUtil 25%). BM=256 x BN=128, fam-split,
// 8 waves (4M x 2N), LDS 128 KiB (A dbuf 64K + B dbuf 64K), 1 block/CU.
// All staging via global_load_lds with swizzle baked into the global source
// address; zero vmcnt(0) drains in the K-loop (counted waits, 2-deep).

#define BROWS 16384
#define DDIM  512

typedef __bf16 bf16x8 __attribute__((ext_vector_type(8)));
typedef __bf16 bf16x4 __attribute__((ext_vector_type(4)));
typedef float  f32x4  __attribute__((ext_vector_type(4)));
typedef float  f32x16 __attribute__((ext_vector_type(16)));

__device__ __forceinline__ float sigf(float x) { return 1.0f / (1.0f + __expf(-x)); }

__device__ __forceinline__ bf16x4 cvt4(f32x4 v) {
    bf16x4 r;
    r[0] = (__bf16)v[0]; r[1] = (__bf16)v[1];
    r[2] = (__bf16)v[2]; r[3] = (__bf16)v[3];
    return r;
}

__device__ __forceinline__ void glds16(const __bf16* g, __bf16* l) {
    __builtin_amdgcn_global_load_lds(
        (const __attribute__((address_space(1))) void*)g,
        (__attribute__((address_space(3))) void*)l, 16, 0, 0);
}

template<int N> __device__ __forceinline__ void waitvm();
template<> __device__ __forceinline__ void waitvm<0>() { asm volatile("s_waitcnt vmcnt(0)" ::: "memory"); }
template<> __device__ __forceinline__ void waitvm<6>() { asm volatile("s_waitcnt vmcnt(6)" ::: "memory"); }
template<> __device__ __forceinline__ void waitvm<8>() { asm volatile("s_waitcnt vmcnt(8)" ::: "memory"); }

// ===================== prepass: X, S, weights -> bf16 =====================
// ws elems: [0) Xb 8388608 | [8388608) Sb 8388608 | [16777216) weights:
//   +0 Wzw 512x1024 | +524288 Wh' 512x512 | +786432 Wzc 512x1024 | +1310720 Wit 512x512
__global__ __launch_bounds__(256)
void petnn_cvt(const float* __restrict__ X,   const float* __restrict__ S,
               const float* __restrict__ Wzw, const float* __restrict__ Wh,
               const float* __restrict__ Wzc, const float* __restrict__ Wit,
               __bf16* __restrict__ ws)
{
    const int i = blockIdx.x * 256 + threadIdx.x;   // f32x4 chunk, 4587520 total
    const float* src; size_t dst;
    if (i < 2097152)      { src = X + (size_t)i * 4; dst = (size_t)i * 4; }
    else if (i < 4194304) { const int j = i - 2097152;
                            src = S + (size_t)j * 4; dst = 8388608 + (size_t)j * 4; }
    else {
        const int j = i - 4194304;                  // 0..393215 (weights)
        if (j < 131072)      { src = Wzw + (size_t)j * 4;
                               dst = 16777216 + (size_t)j * 4; }
        else if (j < 196608) { const int jj = j - 131072;   // Wh cols 0..511
                               src = Wh + (size_t)(jj >> 7) * 1024 + (jj & 127) * 4;
                               dst = 16777216 + 524288 + (size_t)jj * 4; }
        else if (j < 327680) { const int jj = j - 196608;
                               src = Wzc + (size_t)jj * 4;
                               dst = 16777216 + 786432 + (size_t)jj * 4; }
        else                 { const int jj = j - 327680;
                               src = Wit + (size_t)jj * 4;
                               dst = 16777216 + 1310720 + (size_t)jj * 4; }
    }
    *(bf16x4*)(ws + dst) = cvt4(*(const f32x4*)src);
}

// ===================== main: 32x32 MFMA fused GEMM =====================
// BM=256 x BN=128, 2 outputs (P,Q), BK=64, 16 K-steps (Q only kt<8).
// 512 thr = 8 waves 4(M) x 2(N); wave tile 64x64 per output;
// acc = 2(out) x 2(mf) x 2(nf) x f32x16 = 128 VGPR.
// LDS: sA dbuf 2x32K + sB dbuf 2x32K = 128 KiB.
__global__ __launch_bounds__(512, 2)
void petnn_fused3(const __bf16* __restrict__ Xb, const __bf16* __restrict__ Sb,
                  const __bf16* __restrict__ wb,
                  const float* __restrict__ bzw, const float* __restrict__ bh,
                  const float* __restrict__ bzc, const float* __restrict__ bit_,
                  float* __restrict__ out)
{
    __shared__ __align__(16) __bf16 sA[2 * 256 * 64];        // 64 KiB
    __shared__ __align__(16) __bf16 sB[2 * 2 * 128 * 64];    // 64 KiB

    const int tid = threadIdx.x;
    const int bid = blockIdx.x;
    // XCD-chunked swizzle (512 wgs, bijective; HW XCD = bid & 7). Each XCD:
    // 64 consecutive orig = 8 mblk x (4 nblk x 2 fam) -> A panel reused 8x in L2.
    const int orig = (bid & 7) * 64 + (bid >> 3);
    const int fam  = orig & 1;
    const int nblk = (orig >> 1) & 3;
    const int mblk = orig >> 3;          // 0..63

    const int lane = tid & 63, wid = tid >> 6;
    const int wm = wid >> 1;             // 0..3 (64-row slice)
    const int wn = wid & 1;              // 0..1 (64-col slice)
    const int l31 = lane & 31;
    const int hi  = lane >> 5;

    const int arow0 = mblk * 256;
    const int ncol0 = nblk * 128;

    // staging sources (swizzle in GLOBAL address; LDS dest linear):
    // thread t -> row/col (t>>3), chunk (t&7); source chunk = (t&7) ^ (row&7).
    const int gr   = tid >> 3;
    const int gswz = ((tid & 7) ^ (gr & 7)) << 3;
    const __bf16* pXA = Xb + (size_t)(arow0 + gr) * 512 + gswz;
    const __bf16* pSA = Sb + (size_t)(arow0 + gr) * 512 + gswz;
    const __bf16* wbase = wb + (size_t)fam * 786432;
    const __bf16* wP  = wbase + (size_t)(ncol0 + gr) * 1024 + gswz;          // K=1024
    const __bf16* wP2 = wP + 64 * 1024;                                      // cols +64
    const __bf16* wQ  = wbase + 524288 + (size_t)(ncol0 + gr) * 512 + gswz;  // K=512
    const __bf16* wQ2 = wQ + 64 * 512;

    f32x16 accP[2][2] = {}, accQ[2][2] = {};

#define ISSUE_TILE(KTN, FULLT)                                               \
    {                                                                        \
        const __bf16* ab = ((KTN) < 8) ? pXA : pSA;                          \
        const int kga = ((KTN) & 7) * 64;                                    \
        __bf16* da = sA + ((KTN) & 1) * 16384 + tid * 8;                     \
        __bf16* db = sB + ((KTN) & 1) * 16384 + tid * 8;                     \
        glds16(ab + kga, da);                                                \
        glds16(ab + 32768 + kga, da + 4096);                                 \
        glds16(ab + 65536 + kga, da + 8192);                                 \
        glds16(ab + 98304 + kga, da + 12288);                                \
        glds16(wP + (KTN) * 64, db);                                         \
        glds16(wP2 + (KTN) * 64, db + 4096);                                 \
        if (FULLT) {                                                         \
            glds16(wQ + (KTN) * 64, db + 8192);                              \
            glds16(wQ2 + (KTN) * 64, db + 12288);                            \
        }                                                                    \
    }

    // prologue: tiles 0 and 1 (8 glds each; vmcnt order = issue order)
    ISSUE_TILE(0, true)
    ISSUE_TILE(1, true)

#define MFMA_PHASE(KT, FULL_)                                                \
    {                                                                        \
        const __bf16* aB = sA + ((KT) & 1) * 16384;                          \
        const __bf16* bB = sB + ((KT) & 1) * 16384;                          \
        _Pragma("unroll")                                                    \
        for (int kk = 0; kk < 4; ++kk) {                                     \
            const int kidx = kk * 2 + hi;                                    \
            bf16x8 af[2];                                                    \
            _Pragma("unroll")                                                \
            for (int mf = 0; mf < 2; ++mf) {                                 \
                const int r = wm * 64 + mf * 32 + l31;                       \
                af[mf] = *(const bf16x8*)(aB + r * 64 + ((kidx ^ (r & 7)) << 3)); \
            }                                                                \
            _Pragma("unroll")                                                \
            for (int nf = 0; nf < 2; ++nf) {                                 \
                const int c = wn * 64 + nf * 32 + l31;                       \
                const int sw = (kidx ^ (c & 7)) << 3;                        \
                const bf16x8 bP = *(const bf16x8*)(bB + c * 64 + sw);        \
                _Pragma("unroll")                                            \
                for (int mf = 0; mf < 2; ++mf)                               \
                    accP[mf][nf] = __builtin_amdgcn_mfma_f32_32x32x16_bf16(af[mf], bP, accP[mf][nf], 0, 0, 0); \
                if (FULL_) {                                                 \
                    const bf16x8 bQ = *(const bf16x8*)(bB + 8192 + c * 64 + sw); \
                    _Pragma("unroll")                                        \
                    for (int mf = 0; mf < 2; ++mf)                           \
                        accQ[mf][nf] = __builtin_amdgcn_mfma_f32_32x32x16_bf16(af[mf], bQ, accQ[mf][nf], 0, 0, 0); \
                }                                                            \
            }                                                                \
        }                                                                    \
    }

// ISS: 0 = none, 1 = tail tile (A+P, 6 loads), 2 = full tile (A+P+Q, 8 loads)
#define STEP(KT, WAIT, FULL_, ISS)                                           \
    {                                                                        \
        waitvm<WAIT>();                                                      \
        __builtin_amdgcn_sched_barrier(0);                                   \
        __builtin_amdgcn_s_barrier();                                        \
        asm volatile("" ::: "memory");                                       \
        MFMA_PHASE(KT, FULL_)                                                \
        asm volatile("" ::: "memory");                                       \
        __builtin_amdgcn_sched_barrier(0);                                   \
        __builtin_amdgcn_s_barrier();                                        \
        asm volatile("" ::: "memory");                                       \
        if (ISS) ISSUE_TILE((KT) + 2, (ISS) == 2)                            \
    }

    STEP(0, 8, true, 2)  STEP(1, 8, true, 2)  STEP(2, 8, true, 2)
    STEP(3, 8, true, 2)  STEP(4, 8, true, 2)  STEP(5, 8, true, 2)
    STEP(6, 8, true, 1)   // issues tile 8 (A+P only)
    STEP(7, 6, true, 1)   // issues tile 9
    STEP(8, 6, false, 1)  STEP(9, 6, false, 1)  STEP(10, 6, false, 1)
    STEP(11, 6, false, 1) STEP(12, 6, false, 1) STEP(13, 6, false, 1)
    STEP(14, 6, false, 0)
    STEP(15, 0, false, 0)

#undef STEP
#undef MFMA_PHASE
#undef ISSUE_TILE

    // ---- fused epilogue ----
    // 32x32 C/D layout (m74/m101): col = lane&31, row = (reg&3)+8*(reg>>2)+4*(lane>>5)
    const int colb = ncol0 + wn * 64;
    const int rowb = arow0 + wm * 64;
    if (fam == 0) {
        #pragma unroll
        for (int nf = 0; nf < 2; ++nf) {
            const int col = colb + nf * 32 + l31;
            const float vzw = bzw[col], vh = bh[col];
            #pragma unroll
            for (int mf = 0; mf < 2; ++mf) {
                #pragma unroll
                for (int reg = 0; reg < 16; ++reg) {
                    const int rl  = (reg & 3) + 8 * (reg >> 2) + 4 * hi;
                    const int row = rowb + mf * 32 + rl;
                    const size_t off = (size_t)row * DDIM + col;
                    const float zw = sigf(accP[mf][nf][reg] + vzw);
                    const float hh = sigf(accQ[mf][nf][reg] + vh);
                    out[off] = sigf((1.0f - zw) * (float)Sb[off] + zw * hh
                                    + (float)Xb[off]);                 // S_new
                }
            }
        }
    } else {
        #pragma unroll
        for (int nf = 0; nf < 2; ++nf) {
            const int col = colb + nf * 32 + l31;
            const float vzc = bzc[col], vit = bit_[col];
            #pragma unroll
            for (int mf = 0; mf < 2; ++mf) {
                #pragma unroll
                for (int reg = 0; reg < 16; ++reg) {
                    const int rl  = (reg & 3) + 8 * (reg >> 2) + 4 * hi;
                    const int row = rowb + mf * 32 + rl;
                    const size_t off = (size_t)row * DDIM + col;
                    out[(size_t)BROWS * DDIM + off] =
                        (accP[mf][nf][reg] + vzc) + (accQ[mf][nf][reg] + vit); // C_new
                }
            }
        }
    }
}

// ===================== fallback (ws too small): R4 path =====================
__global__ __launch_bounds__(256)
void petnn_cvtw(const float* __restrict__ Wzw, const float* __restrict__ Wh,
                const float* __restrict__ Wzc, const float* __restrict__ Wit,
                __bf16* __restrict__ wb)
{
    const int i = blockIdx.x * 256 + threadIdx.x;
    const float* src; size_t dst;
    if (i < 131072)      { src = Wzw + (size_t)i * 4;  dst = (size_t)i * 4; }
    else if (i < 196608) { const int j = i - 131072;
                           src = Wh + (size_t)(j >> 7) * 1024 + (j & 127) * 4;
                           dst = 524288 + (size_t)j * 4; }
    else if (i < 327680) { const int j = i - 196608;
                           src = Wzc + (size_t)j * 4;  dst = 786432 + (size_t)j * 4; }
    else                 { const int j = i - 327680;
                           src = Wit + (size_t)j * 4;  dst = 1310720 + (size_t)j * 4; }
    *(bf16x4*)(wb + dst) = cvt4(*(const f32x4*)src);
}

__global__ __launch_bounds__(512, 4)
void petnn_fused(const float* __restrict__ X,   const float* __restrict__ S,
                 const __bf16* __restrict__ wb,
                 const float* __restrict__ bzw, const float* __restrict__ bh,
                 const float* __restrict__ bzc, const float* __restrict__ bit_,
                 float* __restrict__ out)
{
    __shared__ __align__(16) __bf16 sA[128 * 64];
    __shared__ __align__(16) __bf16 sB[2 * 2 * 64 * 64];

    const int tid = threadIdx.x;
    const int bid = blockIdx.x;
    const int orig = (bid & 7) * 256 + (bid >> 3);
    const int fam  = orig & 1;
    const int nblk = (orig >> 1) & 7;
    const int mblk = orig >> 4;
    const int lane = tid & 63, wid = tid >> 6;
    const int wm = wid >> 2, wn = wid & 3;
    const int arow0 = mblk * 128, ncol0 = nblk * 64;
    const int srow = tid >> 4, skq = (tid & 15) << 2;
    const int bn = tid >> 3;
    const int bks = ((tid & 7) ^ (bn & 7)) << 3;
    const __bf16* wP = wb + (size_t)fam * 786432 + (size_t)(ncol0 + bn) * 1024 + bks;
    const __bf16* wQ = wb + (size_t)fam * 786432 + 524288 + (size_t)(ncol0 + bn) * 512 + bks;
    __bf16* ldsB = sB + tid * 8;

    f32x4 aP[4] = {}, aQ[4] = {};
    f32x4 ra[4];

    glds16(wP, ldsB);
    glds16(wQ, ldsB + 4096);
    #pragma unroll
    for (int p = 0; p < 4; ++p)
        ra[p] = *(const f32x4*)(X + (size_t)(arow0 + p * 32 + srow) * DDIM + skq);
    glds16(wP + 64, ldsB + 8192);
    glds16(wQ + 64, ldsB + 8192 + 4096);

    for (int kt = 0; kt < 16; ++kt) {
        const bool full = kt < 8;
        #pragma unroll
        for (int p = 0; p < 4; ++p) {
            const int r = p * 32 + srow;
            *(bf16x4*)(sA + r * 64 + (skq ^ ((r & 7) * 8))) = cvt4(ra[p]);
        }
        if (kt + 1 < 16) {
            const float* asrc = (kt + 1 < 8) ? X : S;
            const int kga = ((kt + 1) & 7) * 64 + skq;
            #pragma unroll
            for (int p = 0; p < 4; ++p)
                ra[p] = *(const f32x4*)(asrc + (size_t)(arow0 + p * 32 + srow) * DDIM + kga);
        }
        asm volatile("s_waitcnt lgkmcnt(0)" ::: "memory");
        __builtin_amdgcn_s_barrier();

        const __bf16* bb = sB + (kt & 1) * 8192;
        #pragma unroll
        for (int kk = 0; kk < 2; ++kk) {
            const int kbe = kk * 32 + (lane >> 4) * 8;
            bf16x8 af[4];
            #pragma unroll
            for (int mf = 0; mf < 4; ++mf) {
                const int r = wm * 64 + mf * 16 + (lane & 15);
                af[mf] = *(const bf16x8*)(sA + r * 64 + (kbe ^ ((r & 7) * 8)));
            }
            const int nr = wn * 16 + (lane & 15);
            const int sx = nr * 64 + (kbe ^ ((nr & 7) * 8));
            const bf16x8 bP = *(const bf16x8*)(bb + sx);
            #pragma unroll
            for (int mf = 0; mf < 4; ++mf)
                aP[mf] = __builtin_amdgcn_mfma_f32_16x16x32_bf16(af[mf], bP, aP[mf], 0, 0, 0);
            if (full) {
                const bf16x8 bQ = *(const bf16x8*)(bb + 4096 + sx);
                #pragma unroll
                for (int mf = 0; mf < 4; ++mf)
                    aQ[mf] = __builtin_amdgcn_mfma_f32_16x16x32_bf16(af[mf], bQ, aQ[mf], 0, 0, 0);
            }
        }

        if (kt + 1 < 16) {
            asm volatile("" ::: "memory");
            __builtin_amdgcn_s_barrier();
            asm volatile("" ::: "memory");
            if (kt + 2 < 16) {
                __bf16* bd = sB + (kt & 1) * 8192 + tid * 8;
                glds16(wP + (size_t)(kt + 2) * 64, bd);
                if (kt + 2 < 8) glds16(wQ + (size_t)(kt + 2) * 64, bd + 4096);
            }
        }
    }

    const int col  = ncol0 + wn * 16 + (lane & 15);
    const int rowb = arow0 + wm * 64;
    if (fam == 0) {
        const float vzw = bzw[col], vh = bh[col];
        #pragma unroll
        for (int mf = 0; mf < 4; ++mf) {
            #pragma unroll
            for (int j = 0; j < 4; ++j) {
                const int row = rowb + mf * 16 + ((lane >> 4) << 2) + j;
                const size_t off = (size_t)row * DDIM + col;
                const float zw = sigf(aP[mf][j] + vzw);
                const float hh = sigf(aQ[mf][j] + vh);
                out[off] = sigf((1.0f - zw) * S[off] + zw * hh + X[off]);
            }
        }
    } else {
        const float vzc = bzc[col], vit = bit_[col];
        #pragma unroll
        for (int mf = 0; mf < 4; ++mf) {
            #pragma unroll
            for (int j = 0; j < 4; ++j) {
                const int row = rowb + mf * 16 + ((lane >> 4) << 2) + j;
                const size_t off = (size_t)row * DDIM + col;
                out[(size_t)BROWS * DDIM + off] =
                    (aP[mf][j] + vzc) + (aQ[mf][j] + vit);
            }
        }
    }
}

__global__ void petnn_zeroT(float* __restrict__ t) {
    t[blockIdx.x * 256 + threadIdx.x] = 0.0f;   // T_t == 0 exactly
}

extern "C" void kernel_launch(void* const* d_in, const int* in_sizes, int n_in,
                              void* d_out, int out_size, void* d_ws, size_t ws_size,
                              hipStream_t stream) {
    (void)in_sizes; (void)n_in; (void)out_size;
    const float* X    = (const float*)d_in[0];
    const float* S    = (const float*)d_in[1];
    const float* Wzc  = (const float*)d_in[6];
    const float* bzc  = (const float*)d_in[7];
    const float* Wzw  = (const float*)d_in[8];
    const float* bzw  = (const float*)d_in[9];
    const float* Wit  = (const float*)d_in[10];
    const float* bit_ = (const float*)d_in[11];
    const float* Wh   = (const float*)d_in[14];
    const float* bh   = (const float*)d_in[15];
    float* out = (float*)d_out;

    if (ws_size >= 36700160u) {
        __bf16* ws = (__bf16*)d_ws;
        const __bf16* Xb = ws;
        const __bf16* Sb = ws + 8388608;
        const __bf16* wb = ws + 16777216;
        petnn_cvt<<<dim3(17920), dim3(256), 0, stream>>>(X, S, Wzw, Wh, Wzc, Wit, ws);
        petnn_fused3<<<dim3(512), dim3(512), 0, stream>>>(
            Xb, Sb, wb, bzw, bh, bzc, bit_, out);
    } else {
        __bf16* wb = (__bf16*)d_ws;
        petnn_cvtw<<<dim3(1536), dim3(256), 0, stream>>>(Wzw, Wh, Wzc, Wit, wb);
        petnn_fused<<<dim3(2048), dim3(512), 0, stream>>>(
            X, S, wb, bzw, bh, bzc, bit_, out);
    }
    petnn_zeroT<<<dim3(64), dim3(256), 0, stream>>>(out + 2 * (size_t)BROWS * DDIM);
}

// Round 7
// 101.590 us; speedup vs baseline: 1.3325x; 1.3325x over previous
//
#include <hip/hip_runtime.h>
#include <stdint.h>

// PETNNCell collapse (proven analytically):
//   T_t == 0, m == 1;  C_new = I_t + Z_c;  h = sigmoid(X @ W_h[:, :512]^T + b_h)
//   S_new = sigmoid((1 - Z_w)*S_prev + Z_w*h + X)
//
// R7: 64x64 wave tiles on 16x16x32 MFMA (R6's bytes/FLOP, R5's conflict-free
// read pattern) at 2 blocks/CU. 4-wave blocks, BM=128 x BN=128, fam-split.
// A: glds 2-deep dbuf (32K). B: single 32K buffer, reg-staged (T14) - the
// ds_write's implicit counted vmcnt is the ONLY vmem wait per K-step and
// retires A(kt+1) for free (issued earlier, in-order retirement).

#define BROWS 16384
#define DDIM  512

typedef __bf16 bf16x8 __attribute__((ext_vector_type(8)));
typedef __bf16 bf16x4 __attribute__((ext_vector_type(4)));
typedef float  f32x4  __attribute__((ext_vector_type(4)));

__device__ __forceinline__ float sigf(float x) { return 1.0f / (1.0f + __expf(-x)); }

__device__ __forceinline__ bf16x4 cvt4(f32x4 v) {
    bf16x4 r;
    r[0] = (__bf16)v[0]; r[1] = (__bf16)v[1];
    r[2] = (__bf16)v[2]; r[3] = (__bf16)v[3];
    return r;
}

__device__ __forceinline__ void glds16(const __bf16* g, __bf16* l) {
    __builtin_amdgcn_global_load_lds(
        (const __attribute__((address_space(1))) void*)g,
        (__attribute__((address_space(3))) void*)l, 16, 0, 0);
}

// ===================== prepass: X, S, weights -> bf16 =====================
// ws elems: [0) Xb 8388608 | [8388608) Sb 8388608 | [16777216) weights:
//   +0 Wzw 512x1024 | +524288 Wh' 512x512 | +786432 Wzc 512x1024 | +1310720 Wit 512x512
__global__ __launch_bounds__(256)
void petnn_cvt(const float* __restrict__ X,   const float* __restrict__ S,
               const float* __restrict__ Wzw, const float* __restrict__ Wh,
               const float* __restrict__ Wzc, const float* __restrict__ Wit,
               __bf16* __restrict__ ws)
{
    const int i = blockIdx.x * 256 + threadIdx.x;   // f32x4 chunk, 4587520 total
    const float* src; size_t dst;
    if (i < 2097152)      { src = X + (size_t)i * 4; dst = (size_t)i * 4; }
    else if (i < 4194304) { const int j = i - 2097152;
                            src = S + (size_t)j * 4; dst = 8388608 + (size_t)j * 4; }
    else {
        const int j = i - 4194304;                  // 0..393215 (weights)
        if (j < 131072)      { src = Wzw + (size_t)j * 4;
                               dst = 16777216 + (size_t)j * 4; }
        else if (j < 196608) { const int jj = j - 131072;   // Wh cols 0..511
                               src = Wh + (size_t)(jj >> 7) * 1024 + (jj & 127) * 4;
                               dst = 16777216 + 524288 + (size_t)jj * 4; }
        else if (j < 327680) { const int jj = j - 196608;
                               src = Wzc + (size_t)jj * 4;
                               dst = 16777216 + 786432 + (size_t)jj * 4; }
        else                 { const int jj = j - 327680;
                               src = Wit + (size_t)jj * 4;
                               dst = 16777216 + 1310720 + (size_t)jj * 4; }
    }
    *(bf16x4*)(ws + dst) = cvt4(*(const f32x4*)src);
}

// ===================== main: 64x64 wave tiles, 2 blocks/CU =====================
// BM=128 x BN=128, 2 outputs (P,Q), BK=64, 16 K-steps (Q only kt<8).
// 256 thr = 4 waves 2(M) x 2(N); wave tile 64x64 per output; acc 128 VGPR.
// LDS: sA dbuf 2x16K (glds) + sB single 32K (reg-staged) = 64 KiB.
__global__ __launch_bounds__(256, 2)
void petnn_fused4(const __bf16* __restrict__ Xb, const __bf16* __restrict__ Sb,
                  const __bf16* __restrict__ wb,
                  const float* __restrict__ bzw, const float* __restrict__ bh,
                  const float* __restrict__ bzc, const float* __restrict__ bit_,
                  float* __restrict__ out)
{
    __shared__ __align__(16) __bf16 sA[2 * 128 * 64];   // 32 KiB, glds dbuf
    __shared__ __align__(16) __bf16 sB[2 * 128 * 64];   // 32 KiB: P | Q

    const int tid = threadIdx.x;
    const int bid = blockIdx.x;
    // XCD-chunked swizzle (1024 wgs, bijective; HW XCD = bid & 7). Each XCD:
    // 128 consecutive orig = 16 mblk x (4 nblk x 2 fam) -> A panel 8x L2 reuse.
    const int orig = (bid & 7) * 128 + (bid >> 3);
    const int fam  = orig & 1;
    const int nblk = (orig >> 1) & 3;
    const int mblk = orig >> 3;          // 0..127

    const int lane = tid & 63, wid = tid >> 6;
    const int wm = wid >> 1;             // 0..1 (64-row half)
    const int wn = wid & 1;              // 0..1 (64-col half)
    const int l15 = lane & 15;

    const int arow0 = mblk * 128;
    const int ncol0 = nblk * 128;

    // staging mapping: thread t owns row (t>>3), 16B chunk (t&7); the XOR
    // swizzle is baked into the GLOBAL source address; LDS stays linear.
    const int gr   = tid >> 3;           // 0..31
    const int gswz = ((tid & 7) ^ (gr & 7)) << 3;
    const __bf16* pXA = Xb + (size_t)(arow0 + gr) * 512 + gswz;
    const __bf16* pSA = Sb + (size_t)(arow0 + gr) * 512 + gswz;
    const __bf16* wbase = wb + (size_t)fam * 786432;
    const __bf16* pP = wbase + (size_t)(ncol0 + gr) * 1024 + gswz;           // K=1024
    const __bf16* pQ = wbase + 524288 + (size_t)(ncol0 + gr) * 512 + gswz;   // K=512

    f32x4 aP[4][4] = {}, aQ[4][4] = {};
    bf16x8 rP0, rP1, rP2, rP3, rQ0, rQ1, rQ2, rQ3;   // B staging regs

    // A(kt) -> sA[kt&1]: 4 glds passes of 32 rows each
#define ISSUE_A(KT)                                                          \
    {                                                                        \
        const __bf16* ab = ((KT) < 8) ? pXA : pSA;                           \
        const int kga = ((KT) & 7) * 64;                                     \
        __bf16* d = sA + ((KT) & 1) * 8192 + tid * 8;                        \
        glds16(ab + kga, d);                                                 \
        glds16(ab + 16384 + kga, d + 2048);                                  \
        glds16(ab + 32768 + kga, d + 4096);                                  \
        glds16(ab + 49152 + kga, d + 6144);                                  \
    }

    // B(kt) -> regs (P: rows q*32+gr of 128; Q same when FULLB)
#define LOAD_B(KT, FULLB)                                                    \
    {                                                                        \
        const int kgb = (KT) * 64;                                           \
        rP0 = *(const bf16x8*)(pP + kgb);                                    \
        rP1 = *(const bf16x8*)(pP + 32768 + kgb);                            \
        rP2 = *(const bf16x8*)(pP + 65536 + kgb);                            \
        rP3 = *(const bf16x8*)(pP + 98304 + kgb);                            \
        if (FULLB) {                                                         \
            rQ0 = *(const bf16x8*)(pQ + kgb);                                \
            rQ1 = *(const bf16x8*)(pQ + 16384 + kgb);                        \
            rQ2 = *(const bf16x8*)(pQ + 32768 + kgb);                        \
            rQ3 = *(const bf16x8*)(pQ + 49152 + kgb);                        \
        }                                                                    \
    }

    // regs -> sB (implicit counted vmcnt wait: retires B regs AND the older
    // A(kt+1) glds; kt+2 loads are not yet issued, so nothing is drained)
#define WRITE_B(FULLB)                                                       \
    {                                                                        \
        __bf16* d = sB + tid * 8;                                            \
        *(bf16x8*)(d)        = rP0;                                          \
        *(bf16x8*)(d + 2048) = rP1;                                          \
        *(bf16x8*)(d + 4096) = rP2;                                          \
        *(bf16x8*)(d + 6144) = rP3;                                          \
        if (FULLB) {                                                         \
            *(bf16x8*)(d + 8192)  = rQ0;                                     \
            *(bf16x8*)(d + 10240) = rQ1;                                     \
            *(bf16x8*)(d + 12288) = rQ2;                                     \
            *(bf16x8*)(d + 14336) = rQ3;                                     \
        }                                                                    \
    }

    // ---- prologue ----
    ISSUE_A(0)
    ISSUE_A(1)
    LOAD_B(0, true)
    WRITE_B(true)                        // drains everything (prologue only)
    LOAD_B(1, true)
    asm volatile("s_waitcnt lgkmcnt(0)" ::: "memory");
    __builtin_amdgcn_sched_barrier(0);
    __builtin_amdgcn_s_barrier();
    asm volatile("" ::: "memory");

    for (int kt = 0; kt < 16; ++kt) {
        const bool full = kt < 8;
        // ---- MFMA phase: sA[kt&1] x sB -> acc ----
        const __bf16* aB = sA + (kt & 1) * 8192;
        #pragma unroll
        for (int kk = 0; kk < 2; ++kk) {
            const int kbe = kk * 32 + (lane >> 4) * 8;
            bf16x8 af[4];
            #pragma unroll
            for (int mf = 0; mf < 4; ++mf) {
                const int r = wm * 64 + mf * 16 + l15;
                af[mf] = *(const bf16x8*)(aB + r * 64 + (kbe ^ ((r & 7) * 8)));
            }
            #pragma unroll
            for (int nf = 0; nf < 4; ++nf) {
                const int nr = wn * 64 + nf * 16 + l15;
                const int sx = nr * 64 + (kbe ^ ((nr & 7) * 8));
                const bf16x8 bP = *(const bf16x8*)(sB + sx);
                #pragma unroll
                for (int mf = 0; mf < 4; ++mf)
                    aP[mf][nf] = __builtin_amdgcn_mfma_f32_16x16x32_bf16(af[mf], bP, aP[mf][nf], 0, 0, 0);
                if (full) {
                    const bf16x8 bQ = *(const bf16x8*)(sB + 8192 + sx);
                    #pragma unroll
                    for (int mf = 0; mf < 4; ++mf)
                        aQ[mf][nf] = __builtin_amdgcn_mfma_f32_16x16x32_bf16(af[mf], bQ, aQ[mf][nf], 0, 0, 0);
                }
            }
        }

        // barrier: all waves done reading sA[kt&1] and sB(kt)
        asm volatile("" ::: "memory");
        __builtin_amdgcn_sched_barrier(0);
        __builtin_amdgcn_s_barrier();
        asm volatile("" ::: "memory");

        if (kt + 1 < 16) {
            WRITE_B(kt + 1 < 8)          // the one vmem wait per step
            if (kt + 2 < 16) {
                ISSUE_A(kt + 2)          // into sA[kt&1], just freed
                LOAD_B(kt + 2, kt + 2 < 8)
            }
            asm volatile("s_waitcnt lgkmcnt(0)" ::: "memory");
            __builtin_amdgcn_sched_barrier(0);
            __builtin_amdgcn_s_barrier();
            asm volatile("" ::: "memory");
        }
    }

#undef ISSUE_A
#undef LOAD_B
#undef WRITE_B

    // ---- fused epilogue ----
    // C/D frag layout (m89/m91): col = lane&15, row = (lane>>4)*4 + reg
    const int rowb = arow0 + wm * 64;
    if (fam == 0) {
        #pragma unroll
        for (int nf = 0; nf < 4; ++nf) {
            const int col = ncol0 + wn * 64 + nf * 16 + l15;
            const float vzw = bzw[col], vh = bh[col];
            #pragma unroll
            for (int mf = 0; mf < 4; ++mf) {
                #pragma unroll
                for (int j = 0; j < 4; ++j) {
                    const int row = rowb + mf * 16 + ((lane >> 4) << 2) + j;
                    const size_t off = (size_t)row * DDIM + col;
                    const float zw = sigf(aP[mf][nf][j] + vzw);
                    const float hh = sigf(aQ[mf][nf][j] + vh);
                    out[off] = sigf((1.0f - zw) * (float)Sb[off] + zw * hh
                                    + (float)Xb[off]);                 // S_new
                }
            }
        }
    } else {
        #pragma unroll
        for (int nf = 0; nf < 4; ++nf) {
            const int col = ncol0 + wn * 64 + nf * 16 + l15;
            const float vzc = bzc[col], vit = bit_[col];
            #pragma unroll
            for (int mf = 0; mf < 4; ++mf) {
                #pragma unroll
                for (int j = 0; j < 4; ++j) {
                    const int row = rowb + mf * 16 + ((lane >> 4) << 2) + j;
                    const size_t off = (size_t)row * DDIM + col;
                    out[(size_t)BROWS * DDIM + off] =
                        (aP[mf][nf][j] + vzc) + (aQ[mf][nf][j] + vit); // C_new
                }
            }
        }
    }
}

// ===================== fallback (ws too small): R4 path =====================
__global__ __launch_bounds__(256)
void petnn_cvtw(const float* __restrict__ Wzw, const float* __restrict__ Wh,
                const float* __restrict__ Wzc, const float* __restrict__ Wit,
                __bf16* __restrict__ wb)
{
    const int i = blockIdx.x * 256 + threadIdx.x;
    const float* src; size_t dst;
    if (i < 131072)      { src = Wzw + (size_t)i * 4;  dst = (size_t)i * 4; }
    else if (i < 196608) { const int j = i - 131072;
                           src = Wh + (size_t)(j >> 7) * 1024 + (j & 127) * 4;
                           dst = 524288 + (size_t)j * 4; }
    else if (i < 327680) { const int j = i - 196608;
                           src = Wzc + (size_t)j * 4;  dst = 786432 + (size_t)j * 4; }
    else                 { const int j = i - 327680;
                           src = Wit + (size_t)j * 4;  dst = 1310720 + (size_t)j * 4; }
    *(bf16x4*)(wb + dst) = cvt4(*(const f32x4*)src);
}

__global__ __launch_bounds__(512, 4)
void petnn_fused(const float* __restrict__ X,   const float* __restrict__ S,
                 const __bf16* __restrict__ wb,
                 const float* __restrict__ bzw, const float* __restrict__ bh,
                 const float* __restrict__ bzc, const float* __restrict__ bit_,
                 float* __restrict__ out)
{
    __shared__ __align__(16) __bf16 sA[128 * 64];
    __shared__ __align__(16) __bf16 sB[2 * 2 * 64 * 64];

    const int tid = threadIdx.x;
    const int bid = blockIdx.x;
    const int orig = (bid & 7) * 256 + (bid >> 3);
    const int fam  = orig & 1;
    const int nblk = (orig >> 1) & 7;
    const int mblk = orig >> 4;
    const int lane = tid & 63, wid = tid >> 6;
    const int wm = wid >> 2, wn = wid & 3;
    const int arow0 = mblk * 128, ncol0 = nblk * 64;
    const int srow = tid >> 4, skq = (tid & 15) << 2;
    const int bn = tid >> 3;
    const int bks = ((tid & 7) ^ (bn & 7)) << 3;
    const __bf16* wP = wb + (size_t)fam * 786432 + (size_t)(ncol0 + bn) * 1024 + bks;
    const __bf16* wQ = wb + (size_t)fam * 786432 + 524288 + (size_t)(ncol0 + bn) * 512 + bks;
    __bf16* ldsB = sB + tid * 8;

    f32x4 aP[4] = {}, aQ[4] = {};
    f32x4 ra[4];

    glds16(wP, ldsB);
    glds16(wQ, ldsB + 4096);
    #pragma unroll
    for (int p = 0; p < 4; ++p)
        ra[p] = *(const f32x4*)(X + (size_t)(arow0 + p * 32 + srow) * DDIM + skq);
    glds16(wP + 64, ldsB + 8192);
    glds16(wQ + 64, ldsB + 8192 + 4096);

    for (int kt = 0; kt < 16; ++kt) {
        const bool full = kt < 8;
        #pragma unroll
        for (int p = 0; p < 4; ++p) {
            const int r = p * 32 + srow;
            *(bf16x4*)(sA + r * 64 + (skq ^ ((r & 7) * 8))) = cvt4(ra[p]);
        }
        if (kt + 1 < 16) {
            const float* asrc = (kt + 1 < 8) ? X : S;
            const int kga = ((kt + 1) & 7) * 64 + skq;
            #pragma unroll
            for (int p = 0; p < 4; ++p)
                ra[p] = *(const f32x4*)(asrc + (size_t)(arow0 + p * 32 + srow) * DDIM + kga);
        }
        asm volatile("s_waitcnt lgkmcnt(0)" ::: "memory");
        __builtin_amdgcn_s_barrier();

        const __bf16* bb = sB + (kt & 1) * 8192;
        #pragma unroll
        for (int kk = 0; kk < 2; ++kk) {
            const int kbe = kk * 32 + (lane >> 4) * 8;
            bf16x8 af[4];
            #pragma unroll
            for (int mf = 0; mf < 4; ++mf) {
                const int r = wm * 64 + mf * 16 + (lane & 15);
                af[mf] = *(const bf16x8*)(sA + r * 64 + (kbe ^ ((r & 7) * 8)));
            }
            const int nr = wn * 16 + (lane & 15);
            const int sx = nr * 64 + (kbe ^ ((nr & 7) * 8));
            const bf16x8 bP = *(const bf16x8*)(bb + sx);
            #pragma unroll
            for (int mf = 0; mf < 4; ++mf)
                aP[mf] = __builtin_amdgcn_mfma_f32_16x16x32_bf16(af[mf], bP, aP[mf], 0, 0, 0);
            if (full) {
                const bf16x8 bQ = *(const bf16x8*)(bb + 4096 + sx);
                #pragma unroll
                for (int mf = 0; mf < 4; ++mf)
                    aQ[mf] = __builtin_amdgcn_mfma_f32_16x16x32_bf16(af[mf], bQ, aQ[mf], 0, 0, 0);
            }
        }

        if (kt + 1 < 16) {
            asm volatile("" ::: "memory");
            __builtin_amdgcn_s_barrier();
            asm volatile("" ::: "memory");
            if (kt + 2 < 16) {
                __bf16* bd = sB + (kt & 1) * 8192 + tid * 8;
                glds16(wP + (size_t)(kt + 2) * 64, bd);
                if (kt + 2 < 8) glds16(wQ + (size_t)(kt + 2) * 64, bd + 4096);
            }
        }
    }

    const int col  = ncol0 + wn * 16 + (lane & 15);
    const int rowb = arow0 + wm * 64;
    if (fam == 0) {
        const float vzw = bzw[col], vh = bh[col];
        #pragma unroll
        for (int mf = 0; mf < 4; ++mf) {
            #pragma unroll
            for (int j = 0; j < 4; ++j) {
                const int row = rowb + mf * 16 + ((lane >> 4) << 2) + j;
                const size_t off = (size_t)row * DDIM + col;
                const float zw = sigf(aP[mf][j] + vzw);
                const float hh = sigf(aQ[mf][j] + vh);
                out[off] = sigf((1.0f - zw) * S[off] + zw * hh + X[off]);
            }
        }
    } else {
        const float vzc = bzc[col], vit = bit_[col];
        #pragma unroll
        for (int mf = 0; mf < 4; ++mf) {
            #pragma unroll
            for (int j = 0; j < 4; ++j) {
                const int row = rowb + mf * 16 + ((lane >> 4) << 2) + j;
                const size_t off = (size_t)row * DDIM + col;
                out[(size_t)BROWS * DDIM + off] =
                    (aP[mf][j] + vzc) + (aQ[mf][j] + vit);
            }
        }
    }
}

__global__ void petnn_zeroT(float* __restrict__ t) {
    t[blockIdx.x * 256 + threadIdx.x] = 0.0f;   // T_t == 0 exactly
}

extern "C" void kernel_launch(void* const* d_in, const int* in_sizes, int n_in,
                              void* d_out, int out_size, void* d_ws, size_t ws_size,
                              hipStream_t stream) {
    (void)in_sizes; (void)n_in; (void)out_size;
    const float* X    = (const float*)d_in[0];
    const float* S    = (const float*)d_in[1];
    const float* Wzc  = (const float*)d_in[6];
    const float* bzc  = (const float*)d_in[7];
    const float* Wzw  = (const float*)d_in[8];
    const float* bzw  = (const float*)d_in[9];
    const float* Wit  = (const float*)d_in[10];
    const float* bit_ = (const float*)d_in[11];
    const float* Wh   = (const float*)d_in[14];
    const float* bh   = (const float*)d_in[15];
    float* out = (float*)d_out;

    if (ws_size >= 36700160u) {
        __bf16* ws = (__bf16*)d_ws;
        const __bf16* Xb = ws;
        const __bf16* Sb = ws + 8388608;
        const __bf16* wb = ws + 16777216;
        petnn_cvt<<<dim3(17920), dim3(256), 0, stream>>>(X, S, Wzw, Wh, Wzc, Wit, ws);
        petnn_fused4<<<dim3(1024), dim3(256), 0, stream>>>(
            Xb, Sb, wb, bzw, bh, bzc, bit_, out);
    } else {
        __bf16* wb = (__bf16*)d_ws;
        petnn_cvtw<<<dim3(1536), dim3(256), 0, stream>>>(Wzw, Wh, Wzc, Wit, wb);
        petnn_fused<<<dim3(2048), dim3(512), 0, stream>>>(
            X, S, wb, bzw, bh, bzc, bit_, out);
    }
    petnn_zeroT<<<dim3(64), dim3(256), 0, stream>>>(out + 2 * (size_t)BROWS * DDIM);
}

// Round 8
// 97.600 us; speedup vs baseline: 1.3870x; 1.0409x over previous
//
#include <hip/hip_runtime.h>
#include <stdint.h>

// PETNNCell collapse (proven analytically):
//   T_t == 0, m == 1;  C_new = I_t + Z_c;  h = sigmoid(X @ W_h[:, :512]^T + b_h)
//   S_new = sigmoid((1 - Z_w)*S_prev + Z_w*h + X)
//
// R8: m201-style multi-phase schedule (T3+T4+T5 on top of T2):
// BM=256 x BN=128 per output, fam-split, 8 waves (4M x 2N), 128 KiB LDS,
// 1 block/CU. Per K-tile: 4 phases (P/kk0, Q/kk0, P/kk1, Q/kk1), each
// {issue 1 half-tile glds -> vmcnt(4) counted wait -> barrier -> ds_reads ->
//  lgkmcnt(0) -> setprio(1) 16 MFMA setprio(0) -> barrier}. vmcnt never 0
// in the loop (in-order retirement verified for steady/prologue/transition).

#define BROWS 16384
#define DDIM  512

typedef __bf16 bf16x8 __attribute__((ext_vector_type(8)));
typedef __bf16 bf16x4 __attribute__((ext_vector_type(4)));
typedef float  f32x4  __attribute__((ext_vector_type(4)));

__device__ __forceinline__ float sigf(float x) { return 1.0f / (1.0f + __expf(-x)); }

__device__ __forceinline__ bf16x4 cvt4(f32x4 v) {
    bf16x4 r;
    r[0] = (__bf16)v[0]; r[1] = (__bf16)v[1];
    r[2] = (__bf16)v[2]; r[3] = (__bf16)v[3];
    return r;
}

__device__ __forceinline__ void glds16(const __bf16* g, __bf16* l) {
    __builtin_amdgcn_global_load_lds(
        (const __attribute__((address_space(1))) void*)g,
        (__attribute__((address_space(3))) void*)l, 16, 0, 0);
}

template<int N> __device__ __forceinline__ void waitvm();
template<> __device__ __forceinline__ void waitvm<0>() { asm volatile("s_waitcnt vmcnt(0)" ::: "memory"); }
template<> __device__ __forceinline__ void waitvm<4>() { asm volatile("s_waitcnt vmcnt(4)" ::: "memory"); }

#define BAR   __builtin_amdgcn_s_barrier()
#define SB0   __builtin_amdgcn_sched_barrier(0)
#define LGKM0 asm volatile("s_waitcnt lgkmcnt(0)" ::: "memory")

// ===================== prepass: X, S, weights -> bf16 =====================
// ws elems: [0) Xb 8388608 | [8388608) Sb 8388608 | [16777216) weights:
//   +0 Wzw 512x1024 | +524288 Wh' 512x512 | +786432 Wzc 512x1024 | +1310720 Wit 512x512
__global__ __launch_bounds__(256)
void petnn_cvt(const float* __restrict__ X,   const float* __restrict__ S,
               const float* __restrict__ Wzw, const float* __restrict__ Wh,
               const float* __restrict__ Wzc, const float* __restrict__ Wit,
               __bf16* __restrict__ ws)
{
    const int i = blockIdx.x * 256 + threadIdx.x;   // f32x4 chunk, 4587520 total
    const float* src; size_t dst;
    if (i < 2097152)      { src = X + (size_t)i * 4; dst = (size_t)i * 4; }
    else if (i < 4194304) { const int j = i - 2097152;
                            src = S + (size_t)j * 4; dst = 8388608 + (size_t)j * 4; }
    else {
        const int j = i - 4194304;                  // 0..393215 (weights)
        if (j < 131072)      { src = Wzw + (size_t)j * 4;
                               dst = 16777216 + (size_t)j * 4; }
        else if (j < 196608) { const int jj = j - 131072;   // Wh cols 0..511
                               src = Wh + (size_t)(jj >> 7) * 1024 + (jj & 127) * 4;
                               dst = 16777216 + 524288 + (size_t)jj * 4; }
        else if (j < 327680) { const int jj = j - 196608;
                               src = Wzc + (size_t)jj * 4;
                               dst = 16777216 + 786432 + (size_t)jj * 4; }
        else                 { const int jj = j - 327680;
                               src = Wit + (size_t)jj * 4;
                               dst = 16777216 + 1310720 + (size_t)jj * 4; }
    }
    *(bf16x4*)(ws + dst) = cvt4(*(const f32x4*)src);
}

// ===================== main: 8-phase-style fused GEMM =====================
__global__ __launch_bounds__(512, 2)
void petnn_fused5(const __bf16* __restrict__ Xb, const __bf16* __restrict__ Sb,
                  const __bf16* __restrict__ wb,
                  const float* __restrict__ bzw, const float* __restrict__ bh,
                  const float* __restrict__ bzc, const float* __restrict__ bit_,
                  float* __restrict__ out)
{
    __shared__ __align__(16) __bf16 sA[2 * 256 * 64];       // 64 KiB [par][256r][64k]
    __shared__ __align__(16) __bf16 sB[2 * 2 * 128 * 64];   // 64 KiB [par][P/Q][128c][64k]

    const int tid = threadIdx.x;
    const int bid = blockIdx.x;
    // XCD-chunked swizzle (512 wgs, bijective; HW XCD = bid & 7): per XCD
    // 8 consecutive mblk x (4 nblk x 2 fam) -> A panel shared 8x in L2.
    const int orig = (bid & 7) * 64 + (bid >> 3);
    const int fam  = orig & 1;
    const int nblk = (orig >> 1) & 3;
    const int mblk = orig >> 3;            // 0..63

    const int lane = tid & 63, wid = tid >> 6;
    const int wm = wid >> 1;               // 0..3 (64-row slice of 256)
    const int wn = wid & 1;                // 0..1 (64-col slice of 128)
    const int l15 = lane & 15;
    const int kq  = (lane >> 4) * 8;

    const int arow0 = mblk * 256;
    const int ncol0 = nblk * 128;

    // staging sources (XOR swizzle baked into GLOBAL addr; LDS dest linear):
    // thread t stages row/col (t>>3) of each 64-row group, chunk (t&7).
    const int gr   = tid >> 3;             // 0..63
    const int gswz = ((tid & 7) ^ (gr & 7)) << 3;
    const __bf16* pXA = Xb + (size_t)(arow0 + gr) * 512 + gswz;
    const __bf16* pSA = Sb + (size_t)(arow0 + gr) * 512 + gswz;
    const __bf16* wbase = wb + (size_t)fam * 786432;
    const __bf16* pP  = wbase + (size_t)(ncol0 + gr) * 1024 + gswz;          // K=1024
    const __bf16* pP2 = pP + 64 * 1024;                                      // cols +64
    const __bf16* pQ  = wbase + 524288 + (size_t)(ncol0 + gr) * 512 + gswz;  // K=512
    const __bf16* pQ2 = pQ + 64 * 512;

    // fragment read offsets (elem, within slot)
    int aoff[2][4], boff[2][4];
    #pragma unroll
    for (int f = 0; f < 4; ++f) {
        const int r = wm * 64 + f * 16 + l15;
        aoff[0][f] = r * 64 + (kq        ^ ((r & 7) * 8));
        aoff[1][f] = r * 64 + ((32 + kq) ^ ((r & 7) * 8));
        const int c = wn * 64 + f * 16 + l15;
        boff[0][f] = c * 64 + (kq        ^ ((c & 7) * 8));
        boff[1][f] = c * 64 + ((32 + kq) ^ ((c & 7) * 8));
    }

    f32x4 accP[4][4] = {}, accQ[4][4] = {};

    // half-tile issue units (2 glds = 16 KiB each)
#define ISSUE_AH(T, H) { \
        const __bf16* ab_ = ((T) < 8) ? pXA : pSA; \
        const int kga_ = ((T) & 7) * 64; \
        __bf16* d_ = sA + ((T) & 1) * 16384 + (H) * 8192 + tid * 8; \
        glds16(ab_ + (H) * 65536 + kga_, d_); \
        glds16(ab_ + (H) * 65536 + 32768 + kga_, d_ + 4096); }
#define ISSUE_P(T) { \
        __bf16* d_ = sB + ((T) & 1) * 16384 + tid * 8; \
        glds16(pP  + (T) * 64, d_); \
        glds16(pP2 + (T) * 64, d_ + 4096); }
#define ISSUE_Q(T) { \
        __bf16* d_ = sB + ((T) & 1) * 16384 + 8192 + tid * 8; \
        glds16(pQ  + (T) * 64, d_); \
        glds16(pQ2 + (T) * 64, d_ + 4096); }

#define READ_AF(KK) \
        _Pragma("unroll") \
        for (int mf = 0; mf < 4; ++mf) af[mf] = *(const bf16x8*)(aS_ + aoff[KK][mf]);

    // one phase body: 4 b-frag ds_reads, drain lgkm, prio-wrapped 16 MFMA
#define PH_BODY(ACC, KK, QO) { \
        bf16x8 bv[4]; \
        _Pragma("unroll") \
        for (int nf = 0; nf < 4; ++nf) bv[nf] = *(const bf16x8*)(bS_ + (QO) + boff[KK][nf]); \
        LGKM0; SB0; \
        __builtin_amdgcn_s_setprio(1); \
        _Pragma("unroll") \
        for (int nf = 0; nf < 4; ++nf) \
            _Pragma("unroll") \
            for (int mf = 0; mf < 4; ++mf) \
                ACC[mf][nf] = __builtin_amdgcn_mfma_f32_16x16x32_bf16(af[mf], bv[nf], ACC[mf][nf], 0, 0, 0); \
        __builtin_amdgcn_s_setprio(0); }

    // Full tile (kt<8): 4 phases, issues [AH0, AH1, P, Q] of tile T+1.
#define STEP_FULL(T) { \
        const __bf16* aS_ = sA + ((T) & 1) * 16384; \
        const __bf16* bS_ = sB + ((T) & 1) * 16384; \
        bf16x8 af[4]; \
        /* ph0: P kk0 */ \
        ISSUE_AH((T) + 1, 0) \
        waitvm<4>(); SB0; BAR; SB0; \
        READ_AF(0) PH_BODY(accP, 0, 0) \
        SB0; BAR; \
        /* ph1: Q kk0 */ \
        ISSUE_AH((T) + 1, 1) \
        waitvm<4>(); SB0; BAR; SB0; \
        PH_BODY(accQ, 0, 8192) \
        SB0; BAR; \
        /* ph2: P kk1 */ \
        ISSUE_P((T) + 1) \
        BAR; SB0; \
        READ_AF(1) PH_BODY(accP, 1, 0) \
        SB0; BAR; \
        /* ph3: Q kk1 */ \
        if ((T) + 1 < 8) ISSUE_Q((T) + 1) \
        BAR; SB0; \
        PH_BODY(accQ, 1, 8192) \
        SB0; BAR; }

    // Tail tile (kt>=8, P only): 2 phases, issues [AH0+AH1, P] of tile T+1.
#define STEP_TAIL(T, W) { \
        const __bf16* aS_ = sA + ((T) & 1) * 16384; \
        const __bf16* bS_ = sB + ((T) & 1) * 16384; \
        bf16x8 af[4]; \
        /* ph0: P kk0 */ \
        if ((T) + 1 < 16) { ISSUE_AH((T) + 1, 0) ISSUE_AH((T) + 1, 1) } \
        waitvm<W>(); SB0; BAR; SB0; \
        READ_AF(0) PH_BODY(accP, 0, 0) \
        SB0; BAR; \
        /* ph1: P kk1 */ \
        if ((T) + 1 < 16) ISSUE_P((T) + 1) \
        BAR; SB0; \
        READ_AF(1) PH_BODY(accP, 1, 0) \
        SB0; BAR; }

    // prologue: tile 0's 4 units (8 glds); steady pattern starts at T=0
    ISSUE_AH(0, 0) ISSUE_AH(0, 1) ISSUE_P(0) ISSUE_Q(0)

    STEP_FULL(0) STEP_FULL(1) STEP_FULL(2) STEP_FULL(3)
    STEP_FULL(4) STEP_FULL(5) STEP_FULL(6) STEP_FULL(7)
    STEP_TAIL(8, 4)  STEP_TAIL(9, 4)  STEP_TAIL(10, 4) STEP_TAIL(11, 4)
    STEP_TAIL(12, 4) STEP_TAIL(13, 4) STEP_TAIL(14, 4) STEP_TAIL(15, 0)

#undef STEP_FULL
#undef STEP_TAIL
#undef PH_BODY
#undef READ_AF
#undef ISSUE_AH
#undef ISSUE_P
#undef ISSUE_Q

    // ---- fused epilogue ----
    // C/D frag layout (m89/m91): col = lane&15, row = (lane>>4)*4 + reg
    const int rowb = arow0 + wm * 64;
    const int colb = ncol0 + wn * 64;
    if (fam == 0) {
        #pragma unroll
        for (int nf = 0; nf < 4; ++nf) {
            const int col = colb + nf * 16 + l15;
            const float vzw = bzw[col], vh = bh[col];
            #pragma unroll
            for (int mf = 0; mf < 4; ++mf) {
                #pragma unroll
                for (int j = 0; j < 4; ++j) {
                    const int row = rowb + mf * 16 + ((lane >> 4) << 2) + j;
                    const size_t off = (size_t)row * DDIM + col;
                    const float zw = sigf(accP[mf][nf][j] + vzw);
                    const float hh = sigf(accQ[mf][nf][j] + vh);
                    out[off] = sigf((1.0f - zw) * (float)Sb[off] + zw * hh
                                    + (float)Xb[off]);                 // S_new
                }
            }
        }
    } else {
        #pragma unroll
        for (int nf = 0; nf < 4; ++nf) {
            const int col = colb + nf * 16 + l15;
            const float vzc = bzc[col], vit = bit_[col];
            #pragma unroll
            for (int mf = 0; mf < 4; ++mf) {
                #pragma unroll
                for (int j = 0; j < 4; ++j) {
                    const int row = rowb + mf * 16 + ((lane >> 4) << 2) + j;
                    const size_t off = (size_t)row * DDIM + col;
                    out[(size_t)BROWS * DDIM + off] =
                        (accP[mf][nf][j] + vzc) + (accQ[mf][nf][j] + vit); // C_new
                }
            }
        }
    }
}

// ===================== fallback (ws too small): R4 path =====================
__global__ __launch_bounds__(256)
void petnn_cvtw(const float* __restrict__ Wzw, const float* __restrict__ Wh,
                const float* __restrict__ Wzc, const float* __restrict__ Wit,
                __bf16* __restrict__ wb)
{
    const int i = blockIdx.x * 256 + threadIdx.x;
    const float* src; size_t dst;
    if (i < 131072)      { src = Wzw + (size_t)i * 4;  dst = (size_t)i * 4; }
    else if (i < 196608) { const int j = i - 131072;
                           src = Wh + (size_t)(j >> 7) * 1024 + (j & 127) * 4;
                           dst = 524288 + (size_t)j * 4; }
    else if (i < 327680) { const int j = i - 196608;
                           src = Wzc + (size_t)j * 4;  dst = 786432 + (size_t)j * 4; }
    else                 { const int j = i - 327680;
                           src = Wit + (size_t)j * 4;  dst = 1310720 + (size_t)j * 4; }
    *(bf16x4*)(wb + dst) = cvt4(*(const f32x4*)src);
}

__global__ __launch_bounds__(512, 4)
void petnn_fused(const float* __restrict__ X,   const float* __restrict__ S,
                 const __bf16* __restrict__ wb,
                 const float* __restrict__ bzw, const float* __restrict__ bh,
                 const float* __restrict__ bzc, const float* __restrict__ bit_,
                 float* __restrict__ out)
{
    __shared__ __align__(16) __bf16 sA[128 * 64];
    __shared__ __align__(16) __bf16 sB[2 * 2 * 64 * 64];

    const int tid = threadIdx.x;
    const int bid = blockIdx.x;
    const int orig = (bid & 7) * 256 + (bid >> 3);
    const int fam  = orig & 1;
    const int nblk = (orig >> 1) & 7;
    const int mblk = orig >> 4;
    const int lane = tid & 63, wid = tid >> 6;
    const int wm = wid >> 2, wn = wid & 3;
    const int arow0 = mblk * 128, ncol0 = nblk * 64;
    const int srow = tid >> 4, skq = (tid & 15) << 2;
    const int bn = tid >> 3;
    const int bks = ((tid & 7) ^ (bn & 7)) << 3;
    const __bf16* wP = wb + (size_t)fam * 786432 + (size_t)(ncol0 + bn) * 1024 + bks;
    const __bf16* wQ = wb + (size_t)fam * 786432 + 524288 + (size_t)(ncol0 + bn) * 512 + bks;
    __bf16* ldsB = sB + tid * 8;

    f32x4 aP[4] = {}, aQ[4] = {};
    f32x4 ra[4];

    glds16(wP, ldsB);
    glds16(wQ, ldsB + 4096);
    #pragma unroll
    for (int p = 0; p < 4; ++p)
        ra[p] = *(const f32x4*)(X + (size_t)(arow0 + p * 32 + srow) * DDIM + skq);
    glds16(wP + 64, ldsB + 8192);
    glds16(wQ + 64, ldsB + 8192 + 4096);

    for (int kt = 0; kt < 16; ++kt) {
        const bool full = kt < 8;
        #pragma unroll
        for (int p = 0; p < 4; ++p) {
            const int r = p * 32 + srow;
            *(bf16x4*)(sA + r * 64 + (skq ^ ((r & 7) * 8))) = cvt4(ra[p]);
        }
        if (kt + 1 < 16) {
            const float* asrc = (kt + 1 < 8) ? X : S;
            const int kga = ((kt + 1) & 7) * 64 + skq;
            #pragma unroll
            for (int p = 0; p < 4; ++p)
                ra[p] = *(const f32x4*)(asrc + (size_t)(arow0 + p * 32 + srow) * DDIM + kga);
        }
        asm volatile("s_waitcnt lgkmcnt(0)" ::: "memory");
        __builtin_amdgcn_s_barrier();

        const __bf16* bb = sB + (kt & 1) * 8192;
        #pragma unroll
        for (int kk = 0; kk < 2; ++kk) {
            const int kbe = kk * 32 + (lane >> 4) * 8;
            bf16x8 af[4];
            #pragma unroll
            for (int mf = 0; mf < 4; ++mf) {
                const int r = wm * 64 + mf * 16 + (lane & 15);
                af[mf] = *(const bf16x8*)(sA + r * 64 + (kbe ^ ((r & 7) * 8)));
            }
            const int nr = wn * 16 + (lane & 15);
            const int sx = nr * 64 + (kbe ^ ((nr & 7) * 8));
            const bf16x8 bP = *(const bf16x8*)(bb + sx);
            #pragma unroll
            for (int mf = 0; mf < 4; ++mf)
                aP[mf] = __builtin_amdgcn_mfma_f32_16x16x32_bf16(af[mf], bP, aP[mf], 0, 0, 0);
            if (full) {
                const bf16x8 bQ = *(const bf16x8*)(bb + 4096 + sx);
                #pragma unroll
                for (int mf = 0; mf < 4; ++mf)
                    aQ[mf] = __builtin_amdgcn_mfma_f32_16x16x32_bf16(af[mf], bQ, aQ[mf], 0, 0, 0);
            }
        }

        if (kt + 1 < 16) {
            asm volatile("" ::: "memory");
            __builtin_amdgcn_s_barrier();
            asm volatile("" ::: "memory");
            if (kt + 2 < 16) {
                __bf16* bd = sB + (kt & 1) * 8192 + tid * 8;
                glds16(wP + (size_t)(kt + 2) * 64, bd);
                if (kt + 2 < 8) glds16(wQ + (size_t)(kt + 2) * 64, bd + 4096);
            }
        }
    }

    const int col  = ncol0 + wn * 16 + (lane & 15);
    const int rowb = arow0 + wm * 64;
    if (fam == 0) {
        const float vzw = bzw[col], vh = bh[col];
        #pragma unroll
        for (int mf = 0; mf < 4; ++mf) {
            #pragma unroll
            for (int j = 0; j < 4; ++j) {
                const int row = rowb + mf * 16 + ((lane >> 4) << 2) + j;
                const size_t off = (size_t)row * DDIM + col;
                const float zw = sigf(aP[mf][j] + vzw);
                const float hh = sigf(aQ[mf][j] + vh);
                out[off] = sigf((1.0f - zw) * S[off] + zw * hh + X[off]);
            }
        }
    } else {
        const float vzc = bzc[col], vit = bit_[col];
        #pragma unroll
        for (int mf = 0; mf < 4; ++mf) {
            #pragma unroll
            for (int j = 0; j < 4; ++j) {
                const int row = rowb + mf * 16 + ((lane >> 4) << 2) + j;
                const size_t off = (size_t)row * DDIM + col;
                out[(size_t)BROWS * DDIM + off] =
                    (aP[mf][j] + vzc) + (aQ[mf][j] + vit);
            }
        }
    }
}

__global__ void petnn_zeroT(float* __restrict__ t) {
    t[blockIdx.x * 256 + threadIdx.x] = 0.0f;   // T_t == 0 exactly
}

extern "C" void kernel_launch(void* const* d_in, const int* in_sizes, int n_in,
                              void* d_out, int out_size, void* d_ws, size_t ws_size,
                              hipStream_t stream) {
    (void)in_sizes; (void)n_in; (void)out_size;
    const float* X    = (const float*)d_in[0];
    const float* S    = (const float*)d_in[1];
    const float* Wzc  = (const float*)d_in[6];
    const float* bzc  = (const float*)d_in[7];
    const float* Wzw  = (const float*)d_in[8];
    const float* bzw  = (const float*)d_in[9];
    const float* Wit  = (const float*)d_in[10];
    const float* bit_ = (const float*)d_in[11];
    const float* Wh   = (const float*)d_in[14];
    const float* bh   = (const float*)d_in[15];
    float* out = (float*)d_out;

    if (ws_size >= 36700160u) {
        __bf16* ws = (__bf16*)d_ws;
        const __bf16* Xb = ws;
        const __bf16* Sb = ws + 8388608;
        const __bf16* wb = ws + 16777216;
        petnn_cvt<<<dim3(17920), dim3(256), 0, stream>>>(X, S, Wzw, Wh, Wzc, Wit, ws);
        petnn_fused5<<<dim3(512), dim3(512), 0, stream>>>(
            Xb, Sb, wb, bzw, bh, bzc, bit_, out);
    } else {
        __bf16* wb = (__bf16*)d_ws;
        petnn_cvtw<<<dim3(1536), dim3(256), 0, stream>>>(Wzw, Wh, Wzc, Wit, wb);
        petnn_fused<<<dim3(2048), dim3(512), 0, stream>>>(
            X, S, wb, bzw, bh, bzc, bit_, out);
    }
    petnn_zeroT<<<dim3(64), dim3(256), 0, stream>>>(out + 2 * (size_t)BROWS * DDIM);
}

// Round 9
// 97.018 us; speedup vs baseline: 1.3953x; 1.0060x over previous
//
#include <hip/hip_runtime.h>
#include <stdint.h>

// PETNNCell collapse (proven analytically):
//   T_t == 0, m == 1;  C_new = I_t + Z_c;  h = sigmoid(X @ W_h[:, :512]^T + b_h)
//   S_new = sigmoid((1 - Z_w)*S_prev + Z_w*h + X)
//
// R9: ONE barrier per K-tile, fence-free interior (R8's 8-barrier/phase
// structure paid ~1500 cyc/phase of sync+LDS-latency serialization; the
// compiler schedules ds_read/MFMA near-optimally when left alone).
// Per K-tile: vmcnt(0) [loads issued a full tile earlier -> no stall] ->
// s_barrier -> issue tile T+1's glds -> 24 frag reads + 64 MFMA, compiler-
// scheduled, setprio-wrapped. Geometry from R8: BM=256 x BN=128, fam-split,
// 8 waves (4M x 2N), 64x64 wave tiles, swizzled glds, 128 KiB 2-deep LDS.

#define BROWS 16384
#define DDIM  512

typedef __bf16 bf16x8 __attribute__((ext_vector_type(8)));
typedef __bf16 bf16x4 __attribute__((ext_vector_type(4)));
typedef float  f32x4  __attribute__((ext_vector_type(4)));

__device__ __forceinline__ float sigf(float x) { return 1.0f / (1.0f + __expf(-x)); }

__device__ __forceinline__ bf16x4 cvt4(f32x4 v) {
    bf16x4 r;
    r[0] = (__bf16)v[0]; r[1] = (__bf16)v[1];
    r[2] = (__bf16)v[2]; r[3] = (__bf16)v[3];
    return r;
}

__device__ __forceinline__ void glds16(const __bf16* g, __bf16* l) {
    __builtin_amdgcn_global_load_lds(
        (const __attribute__((address_space(1))) void*)g,
        (__attribute__((address_space(3))) void*)l, 16, 0, 0);
}

#define BAR   __builtin_amdgcn_s_barrier()
#define SB0   __builtin_amdgcn_sched_barrier(0)
#define VM0   asm volatile("s_waitcnt vmcnt(0)" ::: "memory")
#define MEMF  asm volatile("" ::: "memory")

// ===================== prepass: X, S, weights -> bf16 =====================
// ws elems: [0) Xb 8388608 | [8388608) Sb 8388608 | [16777216) weights:
//   +0 Wzw 512x1024 | +524288 Wh' 512x512 | +786432 Wzc 512x1024 | +1310720 Wit 512x512
__global__ __launch_bounds__(256)
void petnn_cvt(const float* __restrict__ X,   const float* __restrict__ S,
               const float* __restrict__ Wzw, const float* __restrict__ Wh,
               const float* __restrict__ Wzc, const float* __restrict__ Wit,
               __bf16* __restrict__ ws)
{
    const int i = blockIdx.x * 256 + threadIdx.x;   // f32x4 chunk, 4587520 total
    const float* src; size_t dst;
    if (i < 2097152)      { src = X + (size_t)i * 4; dst = (size_t)i * 4; }
    else if (i < 4194304) { const int j = i - 2097152;
                            src = S + (size_t)j * 4; dst = 8388608 + (size_t)j * 4; }
    else {
        const int j = i - 4194304;                  // 0..393215 (weights)
        if (j < 131072)      { src = Wzw + (size_t)j * 4;
                               dst = 16777216 + (size_t)j * 4; }
        else if (j < 196608) { const int jj = j - 131072;   // Wh cols 0..511
                               src = Wh + (size_t)(jj >> 7) * 1024 + (jj & 127) * 4;
                               dst = 16777216 + 524288 + (size_t)jj * 4; }
        else if (j < 327680) { const int jj = j - 196608;
                               src = Wzc + (size_t)jj * 4;
                               dst = 16777216 + 786432 + (size_t)jj * 4; }
        else                 { const int jj = j - 327680;
                               src = Wit + (size_t)jj * 4;
                               dst = 16777216 + 1310720 + (size_t)jj * 4; }
    }
    *(bf16x4*)(ws + dst) = cvt4(*(const f32x4*)src);
}

// ===================== main: 1-barrier-per-tile fused GEMM =====================
__global__ __launch_bounds__(512, 2)
void petnn_fused6(const __bf16* __restrict__ Xb, const __bf16* __restrict__ Sb,
                  const __bf16* __restrict__ wb,
                  const float* __restrict__ bzw, const float* __restrict__ bh,
                  const float* __restrict__ bzc, const float* __restrict__ bit_,
                  float* __restrict__ out)
{
    __shared__ __align__(16) __bf16 sA[2 * 256 * 64];       // 64 KiB [par][256r][64k]
    __shared__ __align__(16) __bf16 sB[2 * 2 * 128 * 64];   // 64 KiB [par][P/Q][128c][64k]

    const int tid = threadIdx.x;
    const int bid = blockIdx.x;
    // XCD-chunked swizzle (512 wgs, bijective; HW XCD = bid & 7): per XCD
    // 8 consecutive mblk x (4 nblk x 2 fam) -> A panel shared 8x in L2.
    const int orig = (bid & 7) * 64 + (bid >> 3);
    const int fam  = orig & 1;
    const int nblk = (orig >> 1) & 3;
    const int mblk = orig >> 3;            // 0..63

    const int lane = tid & 63, wid = tid >> 6;
    const int wm = wid >> 1;               // 0..3 (64-row slice of 256)
    const int wn = wid & 1;                // 0..1 (64-col slice of 128)
    const int l15 = lane & 15;
    const int kq  = (lane >> 4) * 8;

    const int arow0 = mblk * 256;
    const int ncol0 = nblk * 128;

    // staging sources (XOR swizzle baked into GLOBAL addr; LDS dest linear):
    // thread t stages row/col (t>>3) of each 64-row group, chunk (t&7).
    const int gr   = tid >> 3;             // 0..63
    const int gswz = ((tid & 7) ^ (gr & 7)) << 3;
    const __bf16* pXA = Xb + (size_t)(arow0 + gr) * 512 + gswz;
    const __bf16* pSA = Sb + (size_t)(arow0 + gr) * 512 + gswz;
    const __bf16* wbase = wb + (size_t)fam * 786432;
    const __bf16* pP  = wbase + (size_t)(ncol0 + gr) * 1024 + gswz;          // K=1024
    const __bf16* pP2 = pP + 64 * 1024;                                      // cols +64
    const __bf16* pQ  = wbase + 524288 + (size_t)(ncol0 + gr) * 512 + gswz;  // K=512
    const __bf16* pQ2 = pQ + 64 * 512;

    // fragment read offsets (elem, within 16384-elem A slot / 8192-elem B half)
    int aoff[2][4], boff[2][4];
    #pragma unroll
    for (int f = 0; f < 4; ++f) {
        const int r = wm * 64 + f * 16 + l15;
        aoff[0][f] = r * 64 + (kq        ^ ((r & 7) * 8));
        aoff[1][f] = r * 64 + ((32 + kq) ^ ((r & 7) * 8));
        const int c = wn * 64 + f * 16 + l15;
        boff[0][f] = c * 64 + (kq        ^ ((c & 7) * 8));
        boff[1][f] = c * 64 + ((32 + kq) ^ ((c & 7) * 8));
    }

    f32x4 accP[4][4] = {}, accQ[4][4] = {};

#define ISSUE_AH(T, H) { \
        const __bf16* ab_ = ((T) < 8) ? pXA : pSA; \
        const int kga_ = ((T) & 7) * 64; \
        __bf16* d_ = sA + ((T) & 1) * 16384 + (H) * 8192 + tid * 8; \
        glds16(ab_ + (H) * 65536 + kga_, d_); \
        glds16(ab_ + (H) * 65536 + 32768 + kga_, d_ + 4096); }
#define ISSUE_P(T) { \
        __bf16* d_ = sB + ((T) & 1) * 16384 + tid * 8; \
        glds16(pP  + (T) * 64, d_); \
        glds16(pP2 + (T) * 64, d_ + 4096); }
#define ISSUE_Q(T) { \
        __bf16* d_ = sB + ((T) & 1) * 16384 + 8192 + tid * 8; \
        glds16(pQ  + (T) * 64, d_); \
        glds16(pQ2 + (T) * 64, d_ + 4096); }

    // one kk half: 12 frag reads + 16/32 MFMA; NO manual fences inside —
    // the compiler interleaves ds_reads under MFMAs with counted lgkmcnt.
#define KK_FULL(KK) { \
        bf16x8 af[4], bp[4], bq[4]; \
        _Pragma("unroll") \
        for (int f = 0; f < 4; ++f) af[f] = *(const bf16x8*)(aS_ + aoff[KK][f]); \
        _Pragma("unroll") \
        for (int f = 0; f < 4; ++f) bp[f] = *(const bf16x8*)(bS_ + boff[KK][f]); \
        _Pragma("unroll") \
        for (int f = 0; f < 4; ++f) bq[f] = *(const bf16x8*)(bS_ + 8192 + boff[KK][f]); \
        __builtin_amdgcn_s_setprio(1); \
        _Pragma("unroll") \
        for (int nf = 0; nf < 4; ++nf) \
            _Pragma("unroll") \
            for (int mf = 0; mf < 4; ++mf) \
                accP[mf][nf] = __builtin_amdgcn_mfma_f32_16x16x32_bf16(af[mf], bp[nf], accP[mf][nf], 0, 0, 0); \
        _Pragma("unroll") \
        for (int nf = 0; nf < 4; ++nf) \
            _Pragma("unroll") \
            for (int mf = 0; mf < 4; ++mf) \
                accQ[mf][nf] = __builtin_amdgcn_mfma_f32_16x16x32_bf16(af[mf], bq[nf], accQ[mf][nf], 0, 0, 0); \
        __builtin_amdgcn_s_setprio(0); }

#define KK_TAIL(KK) { \
        bf16x8 af[4], bp[4]; \
        _Pragma("unroll") \
        for (int f = 0; f < 4; ++f) af[f] = *(const bf16x8*)(aS_ + aoff[KK][f]); \
        _Pragma("unroll") \
        for (int f = 0; f < 4; ++f) bp[f] = *(const bf16x8*)(bS_ + boff[KK][f]); \
        __builtin_amdgcn_s_setprio(1); \
        _Pragma("unroll") \
        for (int nf = 0; nf < 4; ++nf) \
            _Pragma("unroll") \
            for (int mf = 0; mf < 4; ++mf) \
                accP[mf][nf] = __builtin_amdgcn_mfma_f32_16x16x32_bf16(af[mf], bp[nf], accP[mf][nf], 0, 0, 0); \
        __builtin_amdgcn_s_setprio(0); }

    // STEP(T): vmcnt(0) is NOT a stall — tile T's glds were issued at the
    // start of step T-1, a full tile body (~1900 cyc) earlier. The single
    // barrier both publishes tile T's LDS and certifies buf[(T+1)&1] free
    // (every wave's T-1 reads were drained by their MFMA operand waits
    // before it reached this barrier).
#define STEP(T) { \
        VM0; SB0; BAR; \
        if ((T) + 1 < 16) { \
            ISSUE_AH((T) + 1, 0) ISSUE_AH((T) + 1, 1) ISSUE_P((T) + 1) \
            if ((T) + 1 < 8) ISSUE_Q((T) + 1) \
        } \
        MEMF; \
        const __bf16* aS_ = sA + ((T) & 1) * 16384; \
        const __bf16* bS_ = sB + ((T) & 1) * 16384; \
        if ((T) < 8) { KK_FULL(0) KK_FULL(1) } \
        else         { KK_TAIL(0) KK_TAIL(1) } }

    // prologue: tile 0's units only
    ISSUE_AH(0, 0) ISSUE_AH(0, 1) ISSUE_P(0) ISSUE_Q(0)

    STEP(0)  STEP(1)  STEP(2)  STEP(3)
    STEP(4)  STEP(5)  STEP(6)  STEP(7)
    STEP(8)  STEP(9)  STEP(10) STEP(11)
    STEP(12) STEP(13) STEP(14) STEP(15)

#undef STEP
#undef KK_FULL
#undef KK_TAIL
#undef ISSUE_AH
#undef ISSUE_P
#undef ISSUE_Q

    // ---- fused epilogue ----
    // C/D frag layout (m89/m91): col = lane&15, row = (lane>>4)*4 + reg
    const int rowb = arow0 + wm * 64;
    const int colb = ncol0 + wn * 64;
    if (fam == 0) {
        #pragma unroll
        for (int nf = 0; nf < 4; ++nf) {
            const int col = colb + nf * 16 + l15;
            const float vzw = bzw[col], vh = bh[col];
            #pragma unroll
            for (int mf = 0; mf < 4; ++mf) {
                #pragma unroll
                for (int j = 0; j < 4; ++j) {
                    const int row = rowb + mf * 16 + ((lane >> 4) << 2) + j;
                    const size_t off = (size_t)row * DDIM + col;
                    const float zw = sigf(accP[mf][nf][j] + vzw);
                    const float hh = sigf(accQ[mf][nf][j] + vh);
                    out[off] = sigf((1.0f - zw) * (float)Sb[off] + zw * hh
                                    + (float)Xb[off]);                 // S_new
                }
            }
        }
    } else {
        #pragma unroll
        for (int nf = 0; nf < 4; ++nf) {
            const int col = colb + nf * 16 + l15;
            const float vzc = bzc[col], vit = bit_[col];
            #pragma unroll
            for (int mf = 0; mf < 4; ++mf) {
                #pragma unroll
                for (int j = 0; j < 4; ++j) {
                    const int row = rowb + mf * 16 + ((lane >> 4) << 2) + j;
                    const size_t off = (size_t)row * DDIM + col;
                    out[(size_t)BROWS * DDIM + off] =
                        (accP[mf][nf][j] + vzc) + (accQ[mf][nf][j] + vit); // C_new
                }
            }
        }
    }
}

// ===================== fallback (ws too small): R4 path =====================
__global__ __launch_bounds__(256)
void petnn_cvtw(const float* __restrict__ Wzw, const float* __restrict__ Wh,
                const float* __restrict__ Wzc, const float* __restrict__ Wit,
                __bf16* __restrict__ wb)
{
    const int i = blockIdx.x * 256 + threadIdx.x;
    const float* src; size_t dst;
    if (i < 131072)      { src = Wzw + (size_t)i * 4;  dst = (size_t)i * 4; }
    else if (i < 196608) { const int j = i - 131072;
                           src = Wh + (size_t)(j >> 7) * 1024 + (j & 127) * 4;
                           dst = 524288 + (size_t)j * 4; }
    else if (i < 327680) { const int j = i - 196608;
                           src = Wzc + (size_t)j * 4;  dst = 786432 + (size_t)j * 4; }
    else                 { const int j = i - 327680;
                           src = Wit + (size_t)j * 4;  dst = 1310720 + (size_t)j * 4; }
    *(bf16x4*)(wb + dst) = cvt4(*(const f32x4*)src);
}

__global__ __launch_bounds__(512, 4)
void petnn_fused(const float* __restrict__ X,   const float* __restrict__ S,
                 const __bf16* __restrict__ wb,
                 const float* __restrict__ bzw, const float* __restrict__ bh,
                 const float* __restrict__ bzc, const float* __restrict__ bit_,
                 float* __restrict__ out)
{
    __shared__ __align__(16) __bf16 sA[128 * 64];
    __shared__ __align__(16) __bf16 sB[2 * 2 * 64 * 64];

    const int tid = threadIdx.x;
    const int bid = blockIdx.x;
    const int orig = (bid & 7) * 256 + (bid >> 3);
    const int fam  = orig & 1;
    const int nblk = (orig >> 1) & 7;
    const int mblk = orig >> 4;
    const int lane = tid & 63, wid = tid >> 6;
    const int wm = wid >> 2, wn = wid & 3;
    const int arow0 = mblk * 128, ncol0 = nblk * 64;
    const int srow = tid >> 4, skq = (tid & 15) << 2;
    const int bn = tid >> 3;
    const int bks = ((tid & 7) ^ (bn & 7)) << 3;
    const __bf16* wP = wb + (size_t)fam * 786432 + (size_t)(ncol0 + bn) * 1024 + bks;
    const __bf16* wQ = wb + (size_t)fam * 786432 + 524288 + (size_t)(ncol0 + bn) * 512 + bks;
    __bf16* ldsB = sB + tid * 8;

    f32x4 aP[4] = {}, aQ[4] = {};
    f32x4 ra[4];

    glds16(wP, ldsB);
    glds16(wQ, ldsB + 4096);
    #pragma unroll
    for (int p = 0; p < 4; ++p)
        ra[p] = *(const f32x4*)(X + (size_t)(arow0 + p * 32 + srow) * DDIM + skq);
    glds16(wP + 64, ldsB + 8192);
    glds16(wQ + 64, ldsB + 8192 + 4096);

    for (int kt = 0; kt < 16; ++kt) {
        const bool full = kt < 8;
        #pragma unroll
        for (int p = 0; p < 4; ++p) {
            const int r = p * 32 + srow;
            *(bf16x4*)(sA + r * 64 + (skq ^ ((r & 7) * 8))) = cvt4(ra[p]);
        }
        if (kt + 1 < 16) {
            const float* asrc = (kt + 1 < 8) ? X : S;
            const int kga = ((kt + 1) & 7) * 64 + skq;
            #pragma unroll
            for (int p = 0; p < 4; ++p)
                ra[p] = *(const f32x4*)(asrc + (size_t)(arow0 + p * 32 + srow) * DDIM + kga);
        }
        asm volatile("s_waitcnt lgkmcnt(0)" ::: "memory");
        __builtin_amdgcn_s_barrier();

        const __bf16* bb = sB + (kt & 1) * 8192;
        #pragma unroll
        for (int kk = 0; kk < 2; ++kk) {
            const int kbe = kk * 32 + (lane >> 4) * 8;
            bf16x8 af[4];
            #pragma unroll
            for (int mf = 0; mf < 4; ++mf) {
                const int r = wm * 64 + mf * 16 + (lane & 15);
                af[mf] = *(const bf16x8*)(sA + r * 64 + (kbe ^ ((r & 7) * 8)));
            }
            const int nr = wn * 16 + (lane & 15);
            const int sx = nr * 64 + (kbe ^ ((nr & 7) * 8));
            const bf16x8 bP = *(const bf16x8*)(bb + sx);
            #pragma unroll
            for (int mf = 0; mf < 4; ++mf)
                aP[mf] = __builtin_amdgcn_mfma_f32_16x16x32_bf16(af[mf], bP, aP[mf], 0, 0, 0);
            if (full) {
                const bf16x8 bQ = *(const bf16x8*)(bb + 4096 + sx);
                #pragma unroll
                for (int mf = 0; mf < 4; ++mf)
                    aQ[mf] = __builtin_amdgcn_mfma_f32_16x16x32_bf16(af[mf], bQ, aQ[mf], 0, 0, 0);
            }
        }

        if (kt + 1 < 16) {
            asm volatile("" ::: "memory");
            __builtin_amdgcn_s_barrier();
            asm volatile("" ::: "memory");
            if (kt + 2 < 16) {
                __bf16* bd = sB + (kt & 1) * 8192 + tid * 8;
                glds16(wP + (size_t)(kt + 2) * 64, bd);
                if (kt + 2 < 8) glds16(wQ + (size_t)(kt + 2) * 64, bd + 4096);
            }
        }
    }

    const int col  = ncol0 + wn * 16 + (lane & 15);
    const int rowb = arow0 + wm * 64;
    if (fam == 0) {
        const float vzw = bzw[col], vh = bh[col];
        #pragma unroll
        for (int mf = 0; mf < 4; ++mf) {
            #pragma unroll
            for (int j = 0; j < 4; ++j) {
                const int row = rowb + mf * 16 + ((lane >> 4) << 2) + j;
                const size_t off = (size_t)row * DDIM + col;
                const float zw = sigf(aP[mf][j] + vzw);
                const float hh = sigf(aQ[mf][j] + vh);
                out[off] = sigf((1.0f - zw) * S[off] + zw * hh + X[off]);
            }
        }
    } else {
        const float vzc = bzc[col], vit = bit_[col];
        #pragma unroll
        for (int mf = 0; mf < 4; ++mf) {
            #pragma unroll
            for (int j = 0; j < 4; ++j) {
                const int row = rowb + mf * 16 + ((lane >> 4) << 2) + j;
                const size_t off = (size_t)row * DDIM + col;
                out[(size_t)BROWS * DDIM + off] =
                    (aP[mf][j] + vzc) + (aQ[mf][j] + vit);
            }
        }
    }
}

__global__ void petnn_zeroT(float* __restrict__ t) {
    t[blockIdx.x * 256 + threadIdx.x] = 0.0f;   // T_t == 0 exactly
}

extern "C" void kernel_launch(void* const* d_in, const int* in_sizes, int n_in,
                              void* d_out, int out_size, void* d_ws, size_t ws_size,
                              hipStream_t stream) {
    (void)in_sizes; (void)n_in; (void)out_size;
    const float* X    = (const float*)d_in[0];
    const float* S    = (const float*)d_in[1];
    const float* Wzc  = (const float*)d_in[6];
    const float* bzc  = (const float*)d_in[7];
    const float* Wzw  = (const float*)d_in[8];
    const float* bzw  = (const float*)d_in[9];
    const float* Wit  = (const float*)d_in[10];
    const float* bit_ = (const float*)d_in[11];
    const float* Wh   = (const float*)d_in[14];
    const float* bh   = (const float*)d_in[15];
    float* out = (float*)d_out;

    if (ws_size >= 36700160u) {
        __bf16* ws = (__bf16*)d_ws;
        const __bf16* Xb = ws;
        const __bf16* Sb = ws + 8388608;
        const __bf16* wb = ws + 16777216;
        petnn_cvt<<<dim3(17920), dim3(256), 0, stream>>>(X, S, Wzw, Wh, Wzc, Wit, ws);
        petnn_fused6<<<dim3(512), dim3(512), 0, stream>>>(
            Xb, Sb, wb, bzw, bh, bzc, bit_, out);
    } else {
        __bf16* wb = (__bf16*)d_ws;
        petnn_cvtw<<<dim3(1536), dim3(256), 0, stream>>>(Wzw, Wh, Wzc, Wit, wb);
        petnn_fused<<<dim3(2048), dim3(512), 0, stream>>>(
            X, S, wb, bzw, bh, bzc, bit_, out);
    }
    petnn_zeroT<<<dim3(64), dim3(256), 0, stream>>>(out + 2 * (size_t)BROWS * DDIM);
}